// Round 11
// baseline (201.720 us; speedup 1.0000x reference)
//
#include <hip/hip_runtime.h>
#include <hip/hip_fp16.h>

#define NB 16384     // batch rows
#define ND 256       // d_in (GEMM K)
#define NH 1024      // hidden (GEMM N)
#define NK 16        // sparse fan-in

#define REP 8        // PROBE: every variant visible in rocprof top-5

using f16x8 = __attribute__((ext_vector_type(8))) _Float16;
using f32x4 = __attribute__((ext_vector_type(4))) float;

#define C2LOG2E 2.8853900817779268f   // 2*log2(e)

__device__ __forceinline__ void scat8(float (&a)[8], int ii, float ww, int d0) {
#pragma unroll
    for (int e = 0; e < 8; ++e)
        if (ii == d0 + e) a[e] += ww;
}

// ---------------------------------------------------------------------------
// Kernel 1: scatter w1 into FRAGMENT-ORDERED dense Wf (f16). (frozen)
// ---------------------------------------------------------------------------
__global__ __launch_bounds__(128) void build_w_kernel(
        const int* __restrict__ idx, const float* __restrict__ w1,
        _Float16* __restrict__ Wf) {
    int t = blockIdx.x * 128 + threadIdx.x;
    int h = t >> 5;
    int g = t & 31;
    int d0 = g << 3;
    const int4*   ip = reinterpret_cast<const int4*>(idx + h * NK);
    const float4* wp = reinterpret_cast<const float4*>(w1 + h * NK);
    float a[8];
#pragma unroll
    for (int e = 0; e < 8; ++e) a[e] = 0.f;
#pragma unroll
    for (int j = 0; j < 4; ++j) {
        int4   I = ip[j];
        float4 V = wp[j];
        scat8(a, I.x, V.x, d0);
        scat8(a, I.y, V.y, d0);
        scat8(a, I.z, V.z, d0);
        scat8(a, I.w, V.w, d0);
    }
    int c  = h >> 4;
    int ml = h & 15;
    int ks = g >> 2;
    int kg = g & 3;
    size_t off = (((size_t)(c * 8 + ks)) * 64 + kg * 16 + ml) * 8;
    f16x8 o;
#pragma unroll
    for (int e = 0; e < 8; ++e) o[e] = (_Float16)a[e];
    *reinterpret_cast<f16x8*>(&Wf[off]) = o;
}

// ---------------------------------------------------------------------------
// Kernel 2: ABLATION PROBE, template<V>, REP=8 each.
//   V0: full loop (R7 baseline). Writes the real output.
//   V1: MFMA + B-stream, NO tanh epilogue (acc/b1/w2 kept live via asm sinks).
//       Delta vs V0 = epilogue (trans+VALU chain) cost.
//   V2: MFMA + epilogue, NO in-loop B prefetches (B regs reused; asm "+v"
//       rotation defeats cross-iteration CSE). Delta vs V0 = B/L2 cost.
// ---------------------------------------------------------------------------
template<int V>
__global__ __launch_bounds__(512, 2) void fused_probe(
        const float* __restrict__ x, const _Float16* __restrict__ Wf,
        const float* __restrict__ b1, const float* __restrict__ w2,
        const float* __restrict__ b2, float* __restrict__ outp) {
    __shared__ _Float16 lA[64 * 256];
    __shared__ float red[8 * 64];

    const int t = threadIdx.x;
    const int lane = t & 63;
    const int w = t >> 6;
    const int gm0 = blockIdx.x * 64;
    const int ml = lane & 15;
    const int kg = lane >> 4;
    const int start = ((blockIdx.x >> 3) + w) & 7;

    const int sr  = t >> 3;
    const int sub = t & 7;
    const float4* xsrc = reinterpret_cast<const float4*>(
        x + (size_t)(gm0 + sr) * ND + sub * 32);
    float4 v[8];
#pragma unroll
    for (int j = 0; j < 8; ++j) v[j] = xsrc[j];

    const _Float16* gW = Wf + (size_t)w * 32768 + (size_t)lane * 8;
    f16x8 bA[4], bB[4];
    {
        const _Float16* p0 = gW + start * 4096;
#pragma unroll
        for (int ks = 0; ks < 4; ++ks)
            bA[ks] = *reinterpret_cast<const f16x8*>(p0 + ks * 512);
#pragma unroll
        for (int ks = 0; ks < 4; ++ks)
            bB[ks] = *reinterpret_cast<const f16x8*>(p0 + 2048 + ks * 512);
    }

#pragma unroll
    for (int q = 0; q < 4; ++q) {
        int c = sub * 4 + q;
        f16x8 hh;
        hh[0] = (_Float16)v[2*q].x;   hh[1] = (_Float16)v[2*q].y;
        hh[2] = (_Float16)v[2*q].z;   hh[3] = (_Float16)v[2*q].w;
        hh[4] = (_Float16)v[2*q+1].x; hh[5] = (_Float16)v[2*q+1].y;
        hh[6] = (_Float16)v[2*q+1].z; hh[7] = (_Float16)v[2*q+1].w;
        int a16 = sr * 32 + (c ^ (sr & 7));
        *reinterpret_cast<f16x8*>(&lA[a16 * 8]) = hh;
    }
    __syncthreads();

    f16x8 af[4][8];
#pragma unroll
    for (int mi = 0; mi < 4; ++mi)
#pragma unroll
        for (int ks = 0; ks < 8; ++ks) {
            int r = mi * 16 + ml;
            int c = ks * 4 + kg;
            af[mi][ks] = *reinterpret_cast<const f16x8*>(
                &lA[(r * 32 + (c ^ (r & 7))) * 8]);
        }

    float rowpart[4][4];
#pragma unroll
    for (int mi = 0; mi < 4; ++mi)
#pragma unroll
        for (int r4 = 0; r4 < 4; ++r4) rowpart[mi][r4] = 0.f;

#pragma unroll 1
    for (int rep = 0; rep < REP; ++rep) {
#pragma unroll 1
        for (int nc = 0; nc < 8; ++nc) {
            const int ncc = (start + nc) & 7;
            float b1v = b1[w * 128 + ncc * 16 + ml];
            float w2v = w2[w * 128 + ncc * 16 + ml];

            f32x4 acc[4];
#pragma unroll
            for (int mi = 0; mi < 4; ++mi) acc[mi] = f32x4{0.f, 0.f, 0.f, 0.f};

            const int ncn = (start + nc + 1) & 7;
            const _Float16* pn = gW + ncn * 4096;

            if (V == 2) {
                // B stays register-resident; make it "fresh" each iteration
                // so the identical-MFMA loop can't be CSE'd/hoisted.
#pragma unroll
                for (int ks = 0; ks < 4; ++ks) {
                    asm("" : "+v"(bA[ks]));
                    asm("" : "+v"(bB[ks]));
                }
            }

            __builtin_amdgcn_s_setprio(1);
#pragma unroll
            for (int ks = 0; ks < 4; ++ks)
#pragma unroll
                for (int mi = 0; mi < 4; ++mi)
                    acc[mi] = __builtin_amdgcn_mfma_f32_16x16x32_f16(
                        af[mi][ks], bA[ks], acc[mi], 0, 0, 0);
            __builtin_amdgcn_s_setprio(0);
            if (V != 2) {
#pragma unroll
                for (int ks = 0; ks < 4; ++ks)
                    bA[ks] = *reinterpret_cast<const f16x8*>(pn + ks * 512);
            }

            __builtin_amdgcn_s_setprio(1);
#pragma unroll
            for (int ks = 0; ks < 4; ++ks)
#pragma unroll
                for (int mi = 0; mi < 4; ++mi)
                    acc[mi] = __builtin_amdgcn_mfma_f32_16x16x32_f16(
                        af[mi][4 + ks], bB[ks], acc[mi], 0, 0, 0);
            __builtin_amdgcn_s_setprio(0);
            if (V != 2) {
#pragma unroll
                for (int ks = 0; ks < 4; ++ks)
                    bB[ks] = *reinterpret_cast<const f16x8*>(pn + 2048 + ks * 512);
            }

            if (V == 1) {
                // keep MFMA results + b1/w2 loads live without the epilogue
#pragma unroll
                for (int mi = 0; mi < 4; ++mi)
                    asm volatile("" :: "v"(acc[mi]));
                asm volatile("" :: "v"(b1v), "v"(w2v));
            } else {
                float b1c = b1v * C2LOG2E;
#pragma unroll
                for (int mi = 0; mi < 4; ++mi)
#pragma unroll
                    for (int r4 = 0; r4 < 4; ++r4) {
                        float arg = __builtin_fmaf(acc[mi][r4], C2LOG2E, b1c);
                        float e = __builtin_exp2f(arg);
                        float r = __builtin_amdgcn_rcpf(e + 1.0f);
                        float th = __builtin_fmaf(-2.f, r, 1.f);
                        rowpart[mi][r4] = __builtin_fmaf(th, w2v, rowpart[mi][r4]);
                    }
            }
        }
    }

#pragma unroll
    for (int mi = 0; mi < 4; ++mi)
#pragma unroll
        for (int r4 = 0; r4 < 4; ++r4) rowpart[mi][r4] *= (1.0f / REP);

#pragma unroll
    for (int mi = 0; mi < 4; ++mi)
#pragma unroll
        for (int r4 = 0; r4 < 4; ++r4) {
            float vv = rowpart[mi][r4];
            vv += __shfl_xor(vv, 1);
            vv += __shfl_xor(vv, 2);
            vv += __shfl_xor(vv, 4);
            vv += __shfl_xor(vv, 8);
            rowpart[mi][r4] = vv;
        }
    if (ml == 0) {
#pragma unroll
        for (int mi = 0; mi < 4; ++mi)
#pragma unroll
            for (int r4 = 0; r4 < 4; ++r4)
                red[w * 64 + mi * 16 + kg * 4 + r4] = rowpart[mi][r4];
    }
    __syncthreads();

    if (t < 64) {
        float s = 0.f;
#pragma unroll
        for (int j = 0; j < 8; ++j) s += red[j * 64 + t];
        float arg = __builtin_fmaf(s, C2LOG2E, b2[0] * C2LOG2E);
        float e = __builtin_exp2f(arg);
        outp[gm0 + t] = 1.0f - 2.0f * __builtin_amdgcn_rcpf(e + 1.0f);
    }
}

extern "C" void kernel_launch(void* const* d_in, const int* in_sizes, int n_in,
                              void* d_out, int out_size, void* d_ws, size_t ws_size,
                              hipStream_t stream) {
    const float* x   = (const float*)d_in[0];
    const int*   idx = (const int*)d_in[1];
    const float* w1  = (const float*)d_in[2];
    const float* b1  = (const float*)d_in[3];
    const float* w2  = (const float*)d_in[4];
    const float* b2  = (const float*)d_in[5];
    float* out = (float*)d_out;

    _Float16* Wf   = (_Float16*)d_ws;                       // 512 KB
    float* sink1   = (float*)((char*)d_ws + (1u << 20));    // V1 scratch out
    float* sink2   = (float*)((char*)d_ws + (2u << 20));    // V2 scratch out

    build_w_kernel<<<(NH * 32) / 128, 128, 0, stream>>>(idx, w1, Wf);
    fused_probe<1><<<NB / 64, 512, 0, stream>>>(x, Wf, b1, w2, b2, sink1);
    fused_probe<2><<<NB / 64, 512, 0, stream>>>(x, Wf, b1, w2, b2, sink2);
    fused_probe<0><<<NB / 64, 512, 0, stream>>>(x, Wf, b1, w2, b2, out);
}

// Round 12
// 31.246 us; speedup vs baseline: 6.4558x; 6.4558x over previous
//
#include <hip/hip_runtime.h>
#include <hip/hip_fp16.h>

#define NB 16384     // batch rows
#define ND 256       // d_in (GEMM K)
#define NH 1024      // hidden (GEMM N)
#define NK 16        // sparse fan-in

using f16x8 = __attribute__((ext_vector_type(8))) _Float16;
using f32x4 = __attribute__((ext_vector_type(4))) float;

#define C2LOG2E 2.8853900817779268f   // 2*log2(e): tanh(y)=1-2/(2^(y*C2)+1)

__device__ __forceinline__ void scat8(float (&a)[8], int ii, float ww, int d0) {
#pragma unroll
    for (int e = 0; e < 8; ++e)
        if (ii == d0 + e) a[e] += ww;
}

// ---------------------------------------------------------------------------
// Kernel 1: scatter w1 into FRAGMENT-ORDERED dense Wf (f16). (frozen)
// Fragment block (chunk, ks) lives at Wf + chunk*4096 + ks*512 (elements);
// lane l holds 16B at +l*8 -> each B-fragment load is one coalesced 1KB block.
// ---------------------------------------------------------------------------
__global__ __launch_bounds__(128) void build_w_kernel(
        const int* __restrict__ idx, const float* __restrict__ w1,
        _Float16* __restrict__ Wf) {
    int t = blockIdx.x * 128 + threadIdx.x;
    int h = t >> 5;
    int g = t & 31;
    int d0 = g << 3;
    const int4*   ip = reinterpret_cast<const int4*>(idx + h * NK);
    const float4* wp = reinterpret_cast<const float4*>(w1 + h * NK);
    float a[8];
#pragma unroll
    for (int e = 0; e < 8; ++e) a[e] = 0.f;
#pragma unroll
    for (int j = 0; j < 4; ++j) {
        int4   I = ip[j];
        float4 V = wp[j];
        scat8(a, I.x, V.x, d0);
        scat8(a, I.y, V.y, d0);
        scat8(a, I.z, V.z, d0);
        scat8(a, I.w, V.w, d0);
    }
    int c  = h >> 4;
    int ml = h & 15;
    int ks = g >> 2;
    int kg = g & 3;
    size_t off = (((size_t)(c * 8 + ks)) * 64 + kg * 16 + ml) * 8;
    f16x8 o;
#pragma unroll
    for (int e = 0; e < 8; ++e) o[e] = (_Float16)a[e];
    *reinterpret_cast<f16x8*>(&Wf[off]) = o;
}

// ---------------------------------------------------------------------------
// Kernel 2: fused GEMM+tanh+w2-reduce, OCCUPANCY-FIRST restructure.
// R11 ablation: neither epilogue nor B-stream dominates -> loop is MFMA+
// stall bound at 2 waves/SIMD (af[4][8]=128 VGPR pinned occupancy).
// New shape: grid = (M/64) x 2 N-halves = 512 blocks, 512 thr,
// __launch_bounds__(512,4) -> <=128 VGPR -> 2 blocks/CU, 4 waves/SIMD.
// Wave (r,c): rows r*32..+32 (af[2][8] = 64 VGPR), cols c*128 of its N-half.
// r-pairs read the SAME B stream -> L1 absorbs the 2nd read (L2 stays at
// 128 MB/pass). Block emits 64 row-partials (no tanh-final); final kernel
// sums the two N-halves + tanh. No atomics anywhere.
// ---------------------------------------------------------------------------
__global__ __launch_bounds__(512, 4) void fused_kernel(
        const float* __restrict__ x, const _Float16* __restrict__ Wf,
        const float* __restrict__ b1, const float* __restrict__ w2,
        float* __restrict__ partial) {
    __shared__ _Float16 lA[64 * 256];   // 32 KB, 16B chunks swizzled: c ^= (r&7)
    __shared__ float red[4 * 64];       // 1 KB cross-wave (c-groups) reduction

    const int t = threadIdx.x;
    const int lane = t & 63;
    const int w = t >> 6;               // wave 0..7
    const int r = w >> 2;               // row half 0..1
    const int c = w & 3;                // col quarter 0..3
    const int bx = blockIdx.x;          // M slice 0..255
    const int by = blockIdx.y;          // N half 0..1
    const int gm0 = bx * 64;
    const int ml = lane & 15;
    const int kg = lane >> 4;
    // rotation: same for both r-waves of a pair (keeps their B streams identical)
    const int start = (bx + c) & 7;

    // ---- issue x loads (HBM latency overlaps co-resident block's compute) ----
    const int sr  = t >> 3;             // 0..63 staging row
    const int sub = t & 7;              // 32 f32 each
    const float4* xsrc = reinterpret_cast<const float4*>(
        x + (size_t)(gm0 + sr) * ND + sub * 32);
    float4 v[8];
#pragma unroll
    for (int j = 0; j < 8; ++j) v[j] = xsrc[j];

    // ---- stage x tile (64x256) -> LDS f16, swizzled ----
#pragma unroll
    for (int q = 0; q < 4; ++q) {
        int cc = sub * 4 + q;           // 16B chunk index 0..31
        f16x8 hh;
        hh[0] = (_Float16)v[2*q].x;   hh[1] = (_Float16)v[2*q].y;
        hh[2] = (_Float16)v[2*q].z;   hh[3] = (_Float16)v[2*q].w;
        hh[4] = (_Float16)v[2*q+1].x; hh[5] = (_Float16)v[2*q+1].y;
        hh[6] = (_Float16)v[2*q+1].z; hh[7] = (_Float16)v[2*q+1].w;
        int a16 = sr * 32 + (cc ^ (sr & 7));
        *reinterpret_cast<f16x8*>(&lA[a16 * 8]) = hh;
    }
    __syncthreads();

    // ---- pull this wave's A fragments (32 rows) into registers ----
    f16x8 af[2][8];                     // [mi][ks]  (64 VGPR)
#pragma unroll
    for (int mi = 0; mi < 2; ++mi)
#pragma unroll
        for (int ks = 0; ks < 8; ++ks) {
            int row = r * 32 + mi * 16 + ml;
            int cc  = ks * 4 + kg;
            af[mi][ks] = *reinterpret_cast<const f16x8*>(
                &lA[(row * 32 + (cc ^ (row & 7))) * 8]);
        }

    // ---- B stream: this wave's 8 chunks (fragment-ordered Wf, L2/L1-hot) ----
    const int cbase = by * 32 + c * 8;  // global chunk base
    const _Float16* gW = Wf + (size_t)cbase * 4096 + (size_t)lane * 8;
    f16x8 bA[4], bB[4];
    {
        const _Float16* p0 = gW + start * 4096;
#pragma unroll
        for (int ks = 0; ks < 4; ++ks)
            bA[ks] = *reinterpret_cast<const f16x8*>(p0 + ks * 512);
#pragma unroll
        for (int ks = 0; ks < 4; ++ks)
            bB[ks] = *reinterpret_cast<const f16x8*>(p0 + 2048 + ks * 512);
    }

    float rowpart[2][4];
#pragma unroll
    for (int mi = 0; mi < 2; ++mi)
#pragma unroll
        for (int r4 = 0; r4 < 4; ++r4) rowpart[mi][r4] = 0.f;

    const int colbase = (cbase << 4) + ml;   // global col of lane's chunk slot

    // ---- main loop: 8 chunks, runtime loop ----
#pragma unroll 1
    for (int nc = 0; nc < 8; ++nc) {
        const int ncc = (start + nc) & 7;
        float b1v = b1[colbase + ncc * 16];
        float w2v = w2[colbase + ncc * 16];

        f32x4 acc[2];
#pragma unroll
        for (int mi = 0; mi < 2; ++mi) acc[mi] = f32x4{0.f, 0.f, 0.f, 0.f};

        const _Float16* pn = gW + (((start + nc + 1) & 7) * 4096);

        __builtin_amdgcn_s_setprio(1);
#pragma unroll
        for (int ks = 0; ks < 4; ++ks)
#pragma unroll
            for (int mi = 0; mi < 2; ++mi)
                acc[mi] = __builtin_amdgcn_mfma_f32_16x16x32_f16(
                    af[mi][ks], bA[ks], acc[mi], 0, 0, 0);
        __builtin_amdgcn_s_setprio(0);
        if (nc != 7) {
#pragma unroll
            for (int ks = 0; ks < 4; ++ks)
                bA[ks] = *reinterpret_cast<const f16x8*>(pn + ks * 512);
        }

        __builtin_amdgcn_s_setprio(1);
#pragma unroll
        for (int ks = 0; ks < 4; ++ks)
#pragma unroll
            for (int mi = 0; mi < 2; ++mi)
                acc[mi] = __builtin_amdgcn_mfma_f32_16x16x32_f16(
                    af[mi][4 + ks], bB[ks], acc[mi], 0, 0, 0);
        __builtin_amdgcn_s_setprio(0);
        if (nc != 7) {
#pragma unroll
            for (int ks = 0; ks < 4; ++ks)
                bB[ks] = *reinterpret_cast<const f16x8*>(pn + 2048 + ks * 512);
        }

        // epilogue: rowpart += tanh(acc+b1)*w2  (4 VALU + 2 trans / elem)
        float b1c = b1v * C2LOG2E;
#pragma unroll
        for (int mi = 0; mi < 2; ++mi)
#pragma unroll
            for (int r4 = 0; r4 < 4; ++r4) {
                float arg = __builtin_fmaf(acc[mi][r4], C2LOG2E, b1c);
                float e = __builtin_exp2f(arg);
                float rc = __builtin_amdgcn_rcpf(e + 1.0f);
                float th = __builtin_fmaf(-2.f, rc, 1.f);
                rowpart[mi][r4] = __builtin_fmaf(th, w2v, rowpart[mi][r4]);
            }
    }

    // ---- reduce over 16 col-lanes; stash per-c partials in LDS ----
#pragma unroll
    for (int mi = 0; mi < 2; ++mi)
#pragma unroll
        for (int r4 = 0; r4 < 4; ++r4) {
            float vv = rowpart[mi][r4];
            vv += __shfl_xor(vv, 1);
            vv += __shfl_xor(vv, 2);
            vv += __shfl_xor(vv, 4);
            vv += __shfl_xor(vv, 8);
            rowpart[mi][r4] = vv;
        }
    if (ml == 0) {
#pragma unroll
        for (int mi = 0; mi < 2; ++mi)
#pragma unroll
            for (int r4 = 0; r4 < 4; ++r4)
                red[c * 64 + r * 32 + mi * 16 + kg * 4 + r4] = rowpart[mi][r4];
    }
    __syncthreads();

    // ---- cross-c sum -> this N-half's row partial (no tanh yet) ----
    if (t < 64) {
        float s = red[t] + red[64 + t] + red[128 + t] + red[192 + t];
        partial[(size_t)by * NB + gm0 + t] = s;
    }
}

// ---------------------------------------------------------------------------
// Kernel 3: out[i] = tanh(partial[0][i] + partial[1][i] + b2)
// ---------------------------------------------------------------------------
__global__ __launch_bounds__(256) void final_kernel(
        const float* __restrict__ partial, const float* __restrict__ b2,
        float* __restrict__ out) {
    int i = blockIdx.x * 256 + threadIdx.x;
    float s = partial[i] + partial[NB + i] + b2[0];
    float arg = s * C2LOG2E;
    float e = __builtin_exp2f(arg);
    out[i] = 1.0f - 2.0f * __builtin_amdgcn_rcpf(e + 1.0f);
}

extern "C" void kernel_launch(void* const* d_in, const int* in_sizes, int n_in,
                              void* d_out, int out_size, void* d_ws, size_t ws_size,
                              hipStream_t stream) {
    const float* x   = (const float*)d_in[0];
    const int*   idx = (const int*)d_in[1];
    const float* w1  = (const float*)d_in[2];
    const float* b1  = (const float*)d_in[3];
    const float* w2  = (const float*)d_in[4];
    const float* b2  = (const float*)d_in[5];
    float* out = (float*)d_out;

    _Float16* Wf    = (_Float16*)d_ws;                    // 512 KB
    float*    partial = (float*)((char*)d_ws + (1u << 20)); // 2 x 16384 f32

    build_w_kernel<<<(NH * 32) / 128, 128, 0, stream>>>(idx, w1, Wf);
    fused_kernel<<<dim3(NB / 64, 2), 512, 0, stream>>>(x, Wf, b1, w2, partial);
    final_kernel<<<NB / 256, 256, 0, stream>>>(partial, b2, out);
}